// Round 1
// baseline (79.815 us; speedup 1.0000x reference)
//
#include <hip/hip_runtime.h>

#define B_ 8
#define T_ 2048
#define D_ 512
#define BT 256
#define BK 64
#define NT (T_/BT)              /* 8  */
#define NTILES (NT*(NT+1)/2)    /* 36 */

typedef float f32x4 __attribute__((ext_vector_type(4)));
typedef __bf16 bf16x8 __attribute__((ext_vector_type(8)));

// order-preserving float<->uint encoding for atomicMax on possibly-negative floats
__device__ __forceinline__ unsigned encf(float f) {
    int i = __float_as_int(f);
    return (i < 0) ? ~((unsigned)i) : (((unsigned)i) | 0x80000000u);
}
__device__ __forceinline__ float decf(unsigned u) {
    unsigned b = (u & 0x80000000u) ? (u ^ 0x80000000u) : ~u;
    return __int_as_float((int)b);
}

// Kernel 1: per-row 1/max(||x||,1e-12) + init msim slots to encode(-1.0f)
__global__ __launch_bounds__(256) void rownorm_kernel(
        const float* __restrict__ x, float* __restrict__ rnorm,
        unsigned* __restrict__ msim) {
    int row  = blockIdx.x * 4 + (threadIdx.x >> 6);
    int lane = threadIdx.x & 63;
    const float* p = x + (size_t)row * D_ + lane * 8;
    float4 a = *(const float4*)p;
    float4 b = *(const float4*)(p + 4);
    float ss = a.x*a.x + a.y*a.y + a.z*a.z + a.w*a.w
             + b.x*b.x + b.y*b.y + b.z*b.z + b.w*b.w;
#pragma unroll
    for (int m = 32; m; m >>= 1) ss += __shfl_xor(ss, m);
    if (lane == 0) {
        rnorm[row] = 1.0f / fmaxf(sqrtf(ss), 1e-12f);
        msim[row]  = 0x407FFFFFu;   // encf(-1.0f)
    }
}

// Kernel 2: one block per (batch, lower-tri 256x256 tile). MFMA bf16 sim,
// per-row max reduce, atomicMax into msim.
__global__ __launch_bounds__(512, 2) void simmax_kernel(
        const float* __restrict__ x, const float* __restrict__ rnorm,
        unsigned* __restrict__ msim) {
    __shared__ __attribute__((aligned(16))) unsigned short sA[BT * BK];
    __shared__ __attribute__((aligned(16))) unsigned short sB[BT * BK];

    int bid = blockIdx.x;
    int b   = bid & 7;        // batch -> XCD (round-robin dispatch)
    int s   = bid >> 3;       // 0..35 linear lower-tri tile id
    int it  = 0;
    while ((it + 1) * (it + 2) / 2 <= s) it++;
    int jt  = s - it * (it + 1) / 2;

    int tid  = threadIdx.x;
    int lane = tid & 63;
    int wid  = tid >> 6;      // 0..7
    int wr   = wid >> 2;      // 0..1 : wave row  (128 rows each)
    int wc   = wid & 3;       // 0..3 : wave col  (64 cols each)
    int fr   = lane & 15;     // fragment row/col within 16
    int kg   = lane >> 4;     // 0..3 k-group

    const size_t rowA0 = (size_t)b * T_ + (size_t)it * BT;
    const size_t rowB0 = (size_t)b * T_ + (size_t)jt * BT;

    f32x4 acc[8][4];
#pragma unroll
    for (int m = 0; m < 8; m++)
#pragma unroll
        for (int n = 0; n < 4; n++)
            acc[m][n] = (f32x4){0.f, 0.f, 0.f, 0.f};

    // LDS byte offsets (row stride = BK*2 = 128 B). XOR swizzle (row&7)<<4.
    int swz = (fr & 7) << 4;
    int laA = (wr * 128 + fr) * 128 + kg * 16;
    int laB = (wc * 64  + fr) * 128 + kg * 16;

    int trow = tid >> 3;        // 0..63: 64 rows per staging pass
    int tcol = (tid & 7) * 8;   // 8 contiguous floats per thread

    for (int kc = 0; kc < D_ / BK; kc++) {
        int k0 = kc * BK;
        __syncthreads();
#pragma unroll
        for (int p = 0; p < 4; p++) {
            int row = p * 64 + trow;
            int off = (row * 128 + tcol * 2) ^ ((row & 7) << 4);
            {
                const float* g = x + (rowA0 + row) * D_ + k0 + tcol;
                float r  = rnorm[rowA0 + row];
                float4 u = *(const float4*)g;
                float4 v = *(const float4*)(g + 4);
                bf16x8 h;
                h[0] = (__bf16)(u.x * r); h[1] = (__bf16)(u.y * r);
                h[2] = (__bf16)(u.z * r); h[3] = (__bf16)(u.w * r);
                h[4] = (__bf16)(v.x * r); h[5] = (__bf16)(v.y * r);
                h[6] = (__bf16)(v.z * r); h[7] = (__bf16)(v.w * r);
                *(bf16x8*)((char*)sA + off) = h;
            }
            {
                const float* g = x + (rowB0 + row) * D_ + k0 + tcol;
                float r  = rnorm[rowB0 + row];
                float4 u = *(const float4*)g;
                float4 v = *(const float4*)(g + 4);
                bf16x8 h;
                h[0] = (__bf16)(u.x * r); h[1] = (__bf16)(u.y * r);
                h[2] = (__bf16)(u.z * r); h[3] = (__bf16)(u.w * r);
                h[4] = (__bf16)(v.x * r); h[5] = (__bf16)(v.y * r);
                h[6] = (__bf16)(v.z * r); h[7] = (__bf16)(v.w * r);
                *(bf16x8*)((char*)sB + off) = h;
            }
        }
        __syncthreads();
#pragma unroll
        for (int ks = 0; ks < 2; ks++) {
            bf16x8 af[8], bfr[4];
#pragma unroll
            for (int n = 0; n < 4; n++)
                bfr[n] = *(const bf16x8*)((const char*)sB +
                           ((laB + n * 16 * 128 + ks * 64) ^ swz));
#pragma unroll
            for (int m = 0; m < 8; m++)
                af[m] = *(const bf16x8*)((const char*)sA +
                           ((laA + m * 16 * 128 + ks * 64) ^ swz));
#pragma unroll
            for (int m = 0; m < 8; m++)
#pragma unroll
                for (int n = 0; n < 4; n++)
                    acc[m][n] = __builtin_amdgcn_mfma_f32_16x16x32_bf16(
                        af[m], bfr[n], acc[m][n], 0, 0, 0);
        }
    }

    // epilogue: causal mask (diag tiles only) + per-row max + atomicMax
    bool diag = (it == jt);
    unsigned* mrow = msim + (size_t)b * T_ + (size_t)it * BT;
    const float NINF = -__builtin_inff();
#pragma unroll
    for (int m = 0; m < 8; m++) {
#pragma unroll
        for (int e = 0; e < 4; e++) {
            int rloc = wr * 128 + m * 16 + kg * 4 + e;
            float v = NINF;
#pragma unroll
            for (int n = 0; n < 4; n++) {
                int cloc = wc * 64 + n * 16 + fr;
                float t = acc[m][n][e];
                if (diag && cloc >= rloc) t = NINF;
                v = fmaxf(v, t);
            }
            v = fmaxf(v, __shfl_xor(v, 1));
            v = fmaxf(v, __shfl_xor(v, 2));
            v = fmaxf(v, __shfl_xor(v, 4));
            v = fmaxf(v, __shfl_xor(v, 8));
            if (fr == 0) atomicMax(&mrow[rloc], encf(v));
        }
    }
}

// Kernel 3: out = gelu_tanh(x * (1-alpha + alpha*exp(-tau*max_sim)))
__global__ __launch_bounds__(256) void gelu_kernel(
        const float* __restrict__ x, const unsigned* __restrict__ msim,
        const float* __restrict__ ltau, const float* __restrict__ lblend,
        float* __restrict__ out) {
    int i = blockIdx.x * 256 + threadIdx.x;   // float4 index
    float tau   = expf(ltau[0]);
    float alpha = 1.f / (1.f + expf(-lblend[0]));
    int row = i >> 7;                          // D_/4 = 128 float4 per row
    float ms = decf(msim[row]);
    float sc = (1.f - alpha) + alpha * expf(-tau * ms);
    float4 v = ((const float4*)x)[i];
    const float c0 = 0.7978845608028654f;
    const float c1 = 0.044715f;
    float4 o;
    float z;
    z = v.x * sc; o.x = 0.5f * z * (1.f + tanhf(c0 * (z + c1 * z * z * z)));
    z = v.y * sc; o.y = 0.5f * z * (1.f + tanhf(c0 * (z + c1 * z * z * z)));
    z = v.z * sc; o.z = 0.5f * z * (1.f + tanhf(c0 * (z + c1 * z * z * z)));
    z = v.w * sc; o.w = 0.5f * z * (1.f + tanhf(c0 * (z + c1 * z * z * z)));
    ((float4*)out)[i] = o;
}

extern "C" void kernel_launch(void* const* d_in, const int* in_sizes, int n_in,
                              void* d_out, int out_size, void* d_ws, size_t ws_size,
                              hipStream_t stream) {
    (void)in_sizes; (void)n_in; (void)out_size; (void)ws_size;
    const float* x      = (const float*)d_in[0];
    const float* ltau   = (const float*)d_in[1];
    const float* lblend = (const float*)d_in[2];
    float*    out   = (float*)d_out;
    float*    rnorm = (float*)d_ws;
    unsigned* msim  = (unsigned*)((char*)d_ws + (size_t)B_ * T_ * sizeof(float));

    rownorm_kernel<<<B_ * T_ / 4, 256, 0, stream>>>(x, rnorm, msim);
    simmax_kernel<<<B_ * NTILES, 512, 0, stream>>>(x, rnorm, msim);
    gelu_kernel<<<(B_ * T_ * D_ / 4) / 256, 256, 0, stream>>>(x, msim, ltau, lblend, out);
}

// Round 2
// 57.907 us; speedup vs baseline: 1.3783x; 1.3783x over previous
//
#include <hip/hip_runtime.h>

#define B_ 8
#define T_ 2048
#define D_ 512
#define BT 128
#define BK 64
#define NT (T_/BT)              /* 16  */
#define NTILES (NT*(NT+1)/2)    /* 136 */

typedef float f32x4 __attribute__((ext_vector_type(4)));
typedef __bf16 bf16x8 __attribute__((ext_vector_type(8)));

// order-preserving float<->uint encoding for atomicMax on possibly-negative floats
__device__ __forceinline__ unsigned encf(float f) {
    int i = __float_as_int(f);
    return (i < 0) ? ~((unsigned)i) : (((unsigned)i) | 0x80000000u);
}
__device__ __forceinline__ float decf(unsigned u) {
    unsigned b = (u & 0x80000000u) ? (u ^ 0x80000000u) : ~u;
    return __int_as_float((int)b);
}

__device__ __forceinline__ void gload_lds16(const __bf16* g, __bf16* l) {
    __builtin_amdgcn_global_load_lds(
        (const __attribute__((address_space(1))) unsigned int*)g,
        (__attribute__((address_space(3))) unsigned int*)l, 16, 0, 0);
}

// Kernel 1: xn[row] = bf16(x[row] / max(||x[row]||, 1e-12)); init msim to enc(-1)
__global__ __launch_bounds__(256) void rownorm_kernel(
        const float* __restrict__ x, __bf16* __restrict__ xn,
        unsigned* __restrict__ msim) {
    int row  = blockIdx.x * 4 + (threadIdx.x >> 6);
    int lane = threadIdx.x & 63;
    const float* p = x + (size_t)row * D_ + lane * 8;
    float4 a = *(const float4*)p;
    float4 b = *(const float4*)(p + 4);
    float ss = a.x*a.x + a.y*a.y + a.z*a.z + a.w*a.w
             + b.x*b.x + b.y*b.y + b.z*b.z + b.w*b.w;
#pragma unroll
    for (int m = 32; m; m >>= 1) ss += __shfl_xor(ss, m);
    float r = 1.0f / fmaxf(sqrtf(ss), 1e-12f);
    bf16x8 h;
    h[0] = (__bf16)(a.x * r); h[1] = (__bf16)(a.y * r);
    h[2] = (__bf16)(a.z * r); h[3] = (__bf16)(a.w * r);
    h[4] = (__bf16)(b.x * r); h[5] = (__bf16)(b.y * r);
    h[6] = (__bf16)(b.z * r); h[7] = (__bf16)(b.w * r);
    *(bf16x8*)(xn + (size_t)row * D_ + lane * 8) = h;
    if (lane == 0) msim[row] = 0x407FFFFFu;   // encf(-1.0f)
}

// Kernel 2: one block per (batch, lower-tri 128x128 tile). 4 waves (2x2),
// global_load_lds staging from pre-normalized bf16, XOR-swizzled reads.
__global__ __launch_bounds__(256, 4) void simmax_kernel(
        const __bf16* __restrict__ xn, unsigned* __restrict__ msim) {
    __shared__ __attribute__((aligned(16))) __bf16 sA[BT * BK];
    __shared__ __attribute__((aligned(16))) __bf16 sB[BT * BK];

    int bid = blockIdx.x;
    int b   = bid & 7;        // batch -> XCD (round-robin dispatch)
    int s   = bid >> 3;       // 0..135 linear lower-tri tile id
    int it  = 0;
    while ((it + 1) * (it + 2) / 2 <= s) it++;
    int jt  = s - it * (it + 1) / 2;

    int tid  = threadIdx.x;
    int lane = tid & 63;
    int w    = tid >> 6;      // 0..3
    int wr   = w >> 1;        // wave row (64 rows)
    int wc   = w & 1;         // wave col (64 cols)
    int fr   = lane & 15;
    int kg   = lane >> 4;

    const size_t rowA0 = (size_t)b * T_ + (size_t)it * BT;
    const size_t rowB0 = (size_t)b * T_ + (size_t)jt * BT;

    // staging: wave w owns rows [w*32, w*32+32), 8 rows (1024B) per pass.
    // HW writes lane's 16B at ldsbase + lane*16 -> row=lane>>3, chunk=lane&7.
    // LDS stays linear; source chunk pre-swizzled so reads can XOR-deswizzle.
    int rb   = lane >> 3;              // 0..7
    int csrc = (lane & 7) ^ rb;        // pre-swizzled source chunk
    const __bf16* gA0 = xn + (rowA0 + w * 32 + rb) * D_ + csrc * 8;
    const __bf16* gB0 = xn + (rowB0 + w * 32 + rb) * D_ + csrc * 8;
    __bf16* lA0 = sA + (w * 32) * BK;  // wave-uniform LDS base
    __bf16* lB0 = sB + (w * 32) * BK;

    f32x4 acc[4][4];
#pragma unroll
    for (int m = 0; m < 4; m++)
#pragma unroll
        for (int n = 0; n < 4; n++)
            acc[m][n] = (f32x4){0.f, 0.f, 0.f, 0.f};

    int swz = (fr & 7) << 4;
    int laA = (wr * 64 + fr) * 128 + kg * 16;   // byte offsets, row stride 128B
    int laB = (wc * 64 + fr) * 128 + kg * 16;

    for (int kc = 0; kc < D_ / BK; kc++) {
        int k0 = kc * BK;
        __syncthreads();
#pragma unroll
        for (int p = 0; p < 4; p++) {
            gload_lds16(gA0 + (size_t)p * 8 * D_ + k0, lA0 + p * 8 * BK);
            gload_lds16(gB0 + (size_t)p * 8 * D_ + k0, lB0 + p * 8 * BK);
        }
        __syncthreads();
#pragma unroll
        for (int ks = 0; ks < 2; ks++) {
            bf16x8 af[4], bfr[4];
#pragma unroll
            for (int n = 0; n < 4; n++)
                bfr[n] = *(const bf16x8*)((const char*)sB +
                           ((laB + n * 16 * 128 + ks * 64) ^ swz));
#pragma unroll
            for (int m = 0; m < 4; m++)
                af[m] = *(const bf16x8*)((const char*)sA +
                           ((laA + m * 16 * 128 + ks * 64) ^ swz));
#pragma unroll
            for (int m = 0; m < 4; m++)
#pragma unroll
                for (int n = 0; n < 4; n++)
                    acc[m][n] = __builtin_amdgcn_mfma_f32_16x16x32_bf16(
                        af[m], bfr[n], acc[m][n], 0, 0, 0);
        }
    }

    // epilogue: causal mask (diag tiles only) + per-row max + atomicMax
    bool diag = (it == jt);
    unsigned* mrow = msim + (size_t)b * T_ + (size_t)it * BT;
    const float NINF = -__builtin_inff();
#pragma unroll
    for (int m = 0; m < 4; m++) {
#pragma unroll
        for (int e = 0; e < 4; e++) {
            int rloc = wr * 64 + m * 16 + kg * 4 + e;
            float v = NINF;
#pragma unroll
            for (int n = 0; n < 4; n++) {
                int cloc = wc * 64 + n * 16 + fr;
                float t = acc[m][n][e];
                if (diag && cloc >= rloc) t = NINF;
                v = fmaxf(v, t);
            }
            v = fmaxf(v, __shfl_xor(v, 1));
            v = fmaxf(v, __shfl_xor(v, 2));
            v = fmaxf(v, __shfl_xor(v, 4));
            v = fmaxf(v, __shfl_xor(v, 8));
            if (fr == 0) atomicMax(&mrow[rloc], encf(v));
        }
    }
}

// Kernel 3: out = gelu_tanh(x * (1-alpha + alpha*exp(-tau*max_sim)))
__global__ __launch_bounds__(256) void gelu_kernel(
        const float* __restrict__ x, const unsigned* __restrict__ msim,
        const float* __restrict__ ltau, const float* __restrict__ lblend,
        float* __restrict__ out) {
    int i = blockIdx.x * 256 + threadIdx.x;   // float4 index
    float tau   = __expf(ltau[0]);
    float alpha = 1.f / (1.f + __expf(-lblend[0]));
    int row = i >> 7;                          // D_/4 = 128 float4 per row
    float ms = decf(msim[row]);
    float sc = (1.f - alpha) + alpha * __expf(-tau * ms);
    float4 v = ((const float4*)x)[i];
    const float c0 = 0.7978845608028654f;
    const float c1 = 0.044715f;
    float4 o;
#pragma unroll
    for (int j = 0; j < 4; j++) {
        float z = ((const float*)&v)[j] * sc;
        float u = c0 * (z + c1 * z * z * z);
        float t = __expf(2.f * u);
        float th = 1.f - 2.f / (t + 1.f);      // tanh(u), inf-safe
        ((float*)&o)[j] = 0.5f * z * (1.f + th);
    }
    ((float4*)out)[i] = o;
}

extern "C" void kernel_launch(void* const* d_in, const int* in_sizes, int n_in,
                              void* d_out, int out_size, void* d_ws, size_t ws_size,
                              hipStream_t stream) {
    (void)in_sizes; (void)n_in; (void)out_size; (void)ws_size;
    const float* x      = (const float*)d_in[0];
    const float* ltau   = (const float*)d_in[1];
    const float* lblend = (const float*)d_in[2];
    float*    out   = (float*)d_out;
    // xn (16.8 MB) lives in d_out until kernel3 overwrites it; msim in ws.
    __bf16*   xn    = (__bf16*)d_out;
    unsigned* msim  = (unsigned*)d_ws;

    rownorm_kernel<<<B_ * T_ / 4, 256, 0, stream>>>(x, xn, msim);
    simmax_kernel<<<B_ * NTILES, 256, 0, stream>>>(xn, msim);
    gelu_kernel<<<(B_ * T_ * D_ / 4) / 256, 256, 0, stream>>>(x, msim, ltau, lblend, out);
}